// Round 2
// baseline (177.299 us; speedup 1.0000x reference)
//
#include <hip/hip_runtime.h>
#include <stdint.h>

#define Bn 256
#define Tn 50
#define Mn 20
#define En 128
#define G3 384
#define MT 64
#define LDA 132

__device__ __forceinline__ float sigmoidf(float x) {
    return 1.0f / (1.0f + __expf(-x));
}
__device__ __forceinline__ float tanh_safe(float a) {
    float ax = fabsf(a);
    float e2 = __expf(-2.0f * ax);
    return copysignf((1.0f - e2) / (1.0f + e2), a);
}

// ---------------------------------------------------------------------------
// Kernel 1: basket-mean gather -> ub [B*T][128]  (stored in d_out region)
// ---------------------------------------------------------------------------
__global__ __launch_bounds__(256) void gather_kernel(
    const int*   __restrict__ item_ids,
    const int*   __restrict__ basket_sizes,
    const float* __restrict__ emb,
    float* __restrict__ ub)
{
    const int bt   = blockIdx.x * 8 + (threadIdx.x >> 5);
    const int lane = threadIdx.x & 31;
    const int* ids = item_ids + (size_t)bt * Mn;
    float ax = 0.f, ay = 0.f, az = 0.f, aw = 0.f;
    #pragma unroll
    for (int m = 0; m < Mn; ++m) {
        const float4 v = *(const float4*)(emb + (size_t)ids[m] * En + lane * 4);
        ax += v.x; ay += v.y; az += v.z; aw += v.w;
    }
    const float inv = 1.0f / (float)basket_sizes[bt];
    *(float4*)(ub + (size_t)bt * En + lane * 4) =
        make_float4(ax * inv, ay * inv, az * inv, aw * inv);
}

// ---------------------------------------------------------------------------
// Kernel 2: xg = ub @ W_ih^T + b_ih.  1200 blocks (200 M x 6 N); 4x4 tile.
// ---------------------------------------------------------------------------
__global__ __launch_bounds__(256, 2) void gemm_kernel(
    const float* __restrict__ ub,
    const float* __restrict__ W_ih,
    const float* __restrict__ b_ih,
    float* __restrict__ xg)
{
    __shared__ float A[MT][LDA];
    __shared__ float Bt[64][LDA];

    const int tid  = threadIdx.x;
    const int mt   = blockIdx.x / 6;
    const int nc   = blockIdx.x % 6;
    const int row0 = mt * MT;
    const int col0 = nc * 64;

    {
        const int r = tid >> 2, seg = tid & 3;
        const float4* srcA = (const float4*)(ub + (size_t)(row0 + r) * En + seg * 32);
        const float4* srcB = (const float4*)(W_ih + (size_t)(col0 + r) * En + seg * 32);
        float4* dstA = (float4*)&A[r][seg * 32];
        float4* dstB = (float4*)&Bt[r][seg * 32];
        #pragma unroll
        for (int c = 0; c < 8; ++c) { dstA[c] = srcA[c]; dstB[c] = srcB[c]; }
    }
    __syncthreads();

    const int tx = tid & 15;
    const int ty = tid >> 4;

    float acc[4][4];
    #pragma unroll
    for (int i = 0; i < 4; ++i)
        #pragma unroll
        for (int u = 0; u < 4; ++u) acc[i][u] = 0.0f;

    #pragma unroll 4
    for (int k4 = 0; k4 < 32; ++k4) {
        const float4 av[4] = {
            *(const float4*)&A[ty +  0][k4*4], *(const float4*)&A[ty + 16][k4*4],
            *(const float4*)&A[ty + 32][k4*4], *(const float4*)&A[ty + 48][k4*4]};
        const float4 bv[4] = {
            *(const float4*)&Bt[tx +  0][k4*4], *(const float4*)&Bt[tx + 16][k4*4],
            *(const float4*)&Bt[tx + 32][k4*4], *(const float4*)&Bt[tx + 48][k4*4]};
        #pragma unroll
        for (int i = 0; i < 4; ++i)
            #pragma unroll
            for (int u = 0; u < 4; ++u) {
                acc[i][u] = fmaf(av[i].x, bv[u].x, acc[i][u]);
                acc[i][u] = fmaf(av[i].y, bv[u].y, acc[i][u]);
                acc[i][u] = fmaf(av[i].z, bv[u].z, acc[i][u]);
                acc[i][u] = fmaf(av[i].w, bv[u].w, acc[i][u]);
            }
    }

    float bias[4];
    #pragma unroll
    for (int u = 0; u < 4; ++u) bias[u] = b_ih[col0 + tx + 16*u];
    #pragma unroll
    for (int i = 0; i < 4; ++i) {
        const size_t rowoff = (size_t)(row0 + ty + 16*i) * G3;
        #pragma unroll
        for (int u = 0; u < 4; ++u)
            xg[rowoff + col0 + tx + 16*u] = acc[i][u] + bias[u];
    }
}

// ---------------------------------------------------------------------------
// Kernel 3: sequential GRU. 256 blocks x 512 threads (8 waves, 2/SIMD).
// Thread (j in [0,128), q in [0,4)) owns gate rows {j,128+j,256+j} of W_hh,
// cols [q*32,q*32+32); in-wave shfl_xor reduce over q; all q-lanes compute
// the gates redundantly.
//
// ROUND-2 CHANGE (the barrier-drain fix): __syncthreads() emits
// s_waitcnt vmcnt(0) before s_barrier, so every step was draining the xg
// prefetch loads (cold HBM, ~900 cyc) and the outb store -> ~2237 cyc/step.
// Replace with: ds_write -> s_waitcnt lgkmcnt(0) -> raw s_barrier ->
// sched_barrier(0).  LDS correctness is preserved (each wave's own hs reads
// AND its hnew write are drained by its lgkmcnt(0) before the barrier, so
// the single-barrier double-buffer has no read/write race), while global
// loads/stores stay in flight ACROSS the barrier.  xg prefetch deepened to
// 2 steps so its ~900-cyc cold-miss latency is fully covered by ~2 steps of
// compute before the compiler's counted vmcnt at the use point.
// ---------------------------------------------------------------------------
__global__ __launch_bounds__(512, 2) void gru_kernel(
    const int*   __restrict__ lengths,
    const float* __restrict__ W_hh,
    const float* __restrict__ b_hh,
    const float* __restrict__ h0,
    const float* __restrict__ xg,
    float* __restrict__ out_dyn,
    float* __restrict__ out_h)
{
    __shared__ float hs[2][En];

    const int tid = threadIdx.x;
    const int b   = blockIdx.x;
    const int j   = tid >> 2;        // [0,128)
    const int q   = tid & 3;         // [0,4) — low lane bits: shfl_xor stays in-wave

    // Weight fragments, rotated by q at load time so compute indices are constant.
    float4 w0[8], w1[8], w2[8];
    {
        const float4* p0 = (const float4*)(W_hh + (size_t)(0*En + j) * En + q * 32);
        const float4* p1 = (const float4*)(W_hh + (size_t)(1*En + j) * En + q * 32);
        const float4* p2 = (const float4*)(W_hh + (size_t)(2*En + j) * En + q * 32);
        #pragma unroll
        for (int c = 0; c < 8; ++c) {
            const int cc = (c + 2*q) & 7;
            w0[c] = p0[cc]; w1[c] = p1[cc]; w2[c] = p2[cc];
        }
    }

    const int len = lengths[b];
    const float* xgb = xg + (size_t)b * Tn * G3;
    float* outb = out_dyn + (size_t)b * Tn * En;

    const float br = b_hh[j], bz = b_hh[En + j], bn = b_hh[2*En + j];
    float hprev = h0[(size_t)b * En + j];
    if (q == 0) hs[0][j] = hprev;

    // xg software pipeline, depth 2: x0 = step t, x1 = step t+1.
    float x0r = xgb[j], x0z = xgb[En + j], x0n = xgb[2*En + j];
    const int t1 = (1 < len) ? 1 : 0;
    float x1r = xgb[t1*G3 + j], x1z = xgb[t1*G3 + En + j], x1n = xgb[t1*G3 + 2*En + j];
    __syncthreads();   // one-time full drain: hs[0] + weights + x0/x1 resident

    int cur = 0;
    for (int t = 0; t < len; ++t) {
        // issue prefetch for t+2 at the top: ~2 steps of latency-hiding window
        const int tn = (t + 2 < len) ? t + 2 : len - 1;
        const float fr  = xgb[tn*G3 + j];
        const float fz  = xgb[tn*G3 + En + j];
        const float fnn = xgb[tn*G3 + 2*En + j];

        // partial dots over this thread's 32-col K-slice (bank-conflict-free
        // via the rotated walk)
        const float4* h4 = ((const float4*)hs[cur]) + q * 8;
        float a0 = 0.f, a1 = 0.f, a2 = 0.f;
        #pragma unroll
        for (int c = 0; c < 8; ++c) {
            const float4 hv = h4[(c + 2*q) & 7];
            a0 = fmaf(w0[c].x, hv.x, a0); a0 = fmaf(w0[c].y, hv.y, a0);
            a0 = fmaf(w0[c].z, hv.z, a0); a0 = fmaf(w0[c].w, hv.w, a0);
            a1 = fmaf(w1[c].x, hv.x, a1); a1 = fmaf(w1[c].y, hv.y, a1);
            a1 = fmaf(w1[c].z, hv.z, a1); a1 = fmaf(w1[c].w, hv.w, a1);
            a2 = fmaf(w2[c].x, hv.x, a2); a2 = fmaf(w2[c].y, hv.y, a2);
            a2 = fmaf(w2[c].z, hv.z, a2); a2 = fmaf(w2[c].w, hv.w, a2);
        }

        // in-wave butterfly reduce over q (lanes 1, 2 apart)
        a0 += __shfl_xor(a0, 1); a0 += __shfl_xor(a0, 2);
        a1 += __shfl_xor(a1, 1); a1 += __shfl_xor(a1, 2);
        a2 += __shfl_xor(a2, 1); a2 += __shfl_xor(a2, 2);

        // gates — computed redundantly by all 4 q-lanes
        const float r = sigmoidf(x0r + br + a0);
        const float z = sigmoidf(x0z + bz + a1);
        const float n = tanh_safe(x0n + r * (bn + a2));
        const float hnew = (1.0f - z) * n + z * hprev;

        if (q == 0) {
            hs[cur ^ 1][j] = hnew;      // write the OTHER buffer
            outb[t*En + j] = hnew;      // fire-and-forget: never drained in-loop
        }
        // Raw barrier: drain LDS only (own reads + the hnew write), leave
        // global loads/stores in flight across the barrier.
        asm volatile("s_waitcnt lgkmcnt(0)" ::: "memory");
        __builtin_amdgcn_s_barrier();
        __builtin_amdgcn_sched_barrier(0);

        hprev = hnew;
        x0r = x1r; x0z = x1z; x0n = x1n;
        x1r = fr;  x1z = fz;  x1n = fnn;
        cur ^= 1;
    }

    if (q == 0) {
        for (int t = len; t < Tn; ++t) outb[t*En + j] = 0.0f;
        out_h[(size_t)b * En + j] = hprev;
    }
}

extern "C" void kernel_launch(void* const* d_in, const int* in_sizes, int n_in,
                              void* d_out, int out_size, void* d_ws, size_t ws_size,
                              hipStream_t stream) {
    const int*   item_ids     = (const int*)d_in[0];
    const int*   basket_sizes = (const int*)d_in[1];
    const int*   lengths      = (const int*)d_in[2];
    const float* emb          = (const float*)d_in[3];
    const float* W_ih         = (const float*)d_in[4];
    const float* W_hh         = (const float*)d_in[5];
    const float* b_ih         = (const float*)d_in[6];
    const float* b_hh         = (const float*)d_in[7];
    const float* h0           = (const float*)d_in[8];
    float* out = (float*)d_out;
    float* xg  = (float*)d_ws;   // 19.7 MB
    float* ub  = out;            // reuse out_dyn region; overwritten by gru later

    gather_kernel<<<(Bn * Tn) / 8, 256, 0, stream>>>(item_ids, basket_sizes, emb, ub);
    gemm_kernel<<<1200, 256, 0, stream>>>(ub, W_ih, b_ih, xg);
    gru_kernel<<<Bn, 512, 0, stream>>>(
        lengths, W_hh, b_hh, h0, xg, out, out + (size_t)Bn * Tn * En);
}

// Round 3
// 172.608 us; speedup vs baseline: 1.0272x; 1.0272x over previous
//
#include <hip/hip_runtime.h>
#include <stdint.h>

#define Bn 256
#define Tn 50
#define Mn 20
#define En 128
#define G3 384
#define MT 64
#define LDA 132

typedef float f32x4 __attribute__((ext_vector_type(4)));

__device__ __forceinline__ float sigmoidf(float x) {
    return 1.0f / (1.0f + __expf(-x));
}
__device__ __forceinline__ float tanh_safe(float a) {
    float ax = fabsf(a);
    float e2 = __expf(-2.0f * ax);
    return copysignf((1.0f - e2) / (1.0f + e2), a);
}

// DPP quad_perm butterfly adds over the 4-lane quad (q = tid&3).
// Pure VALU (~4 cyc) instead of ds_swizzle (~120 cyc + LDS pipe).
__device__ __forceinline__ float quad_reduce_add(float x) {
    int t1 = __builtin_amdgcn_update_dpp(0, __float_as_int(x),
                                         0xB1 /*[1,0,3,2]*/, 0xF, 0xF, true);
    x += __int_as_float(t1);
    int t2 = __builtin_amdgcn_update_dpp(0, __float_as_int(x),
                                         0x4E /*[2,3,0,1]*/, 0xF, 0xF, true);
    x += __int_as_float(t2);
    return x;   // all 4 lanes of the quad hold the total
}

// ---------------------------------------------------------------------------
// Kernel 1: basket-mean gather -> ub [B*T][128]  (stored in d_out region)
// ---------------------------------------------------------------------------
__global__ __launch_bounds__(256) void gather_kernel(
    const int*   __restrict__ item_ids,
    const int*   __restrict__ basket_sizes,
    const float* __restrict__ emb,
    float* __restrict__ ub)
{
    const int bt   = blockIdx.x * 8 + (threadIdx.x >> 5);
    const int lane = threadIdx.x & 31;
    const int* ids = item_ids + (size_t)bt * Mn;
    float ax = 0.f, ay = 0.f, az = 0.f, aw = 0.f;
    #pragma unroll
    for (int m = 0; m < Mn; ++m) {
        const float4 v = *(const float4*)(emb + (size_t)ids[m] * En + lane * 4);
        ax += v.x; ay += v.y; az += v.z; aw += v.w;
    }
    const float inv = 1.0f / (float)basket_sizes[bt];
    *(float4*)(ub + (size_t)bt * En + lane * 4) =
        make_float4(ax * inv, ay * inv, az * inv, aw * inv);
}

// ---------------------------------------------------------------------------
// Kernel 2: xg = ub @ W_ih^T + b_ih.  1200 blocks (200 M x 6 N); 4x4 tile.
// ---------------------------------------------------------------------------
__global__ __launch_bounds__(256, 2) void gemm_kernel(
    const float* __restrict__ ub,
    const float* __restrict__ W_ih,
    const float* __restrict__ b_ih,
    float* __restrict__ xg)
{
    __shared__ float A[MT][LDA];
    __shared__ float Bt[64][LDA];

    const int tid  = threadIdx.x;
    const int mt   = blockIdx.x / 6;
    const int nc   = blockIdx.x % 6;
    const int row0 = mt * MT;
    const int col0 = nc * 64;

    {
        const int r = tid >> 2, seg = tid & 3;
        const float4* srcA = (const float4*)(ub + (size_t)(row0 + r) * En + seg * 32);
        const float4* srcB = (const float4*)(W_ih + (size_t)(col0 + r) * En + seg * 32);
        float4* dstA = (float4*)&A[r][seg * 32];
        float4* dstB = (float4*)&Bt[r][seg * 32];
        #pragma unroll
        for (int c = 0; c < 8; ++c) { dstA[c] = srcA[c]; dstB[c] = srcB[c]; }
    }
    __syncthreads();

    const int tx = tid & 15;
    const int ty = tid >> 4;

    float acc[4][4];
    #pragma unroll
    for (int i = 0; i < 4; ++i)
        #pragma unroll
        for (int u = 0; u < 4; ++u) acc[i][u] = 0.0f;

    #pragma unroll 4
    for (int k4 = 0; k4 < 32; ++k4) {
        const float4 av[4] = {
            *(const float4*)&A[ty +  0][k4*4], *(const float4*)&A[ty + 16][k4*4],
            *(const float4*)&A[ty + 32][k4*4], *(const float4*)&A[ty + 48][k4*4]};
        const float4 bv[4] = {
            *(const float4*)&Bt[tx +  0][k4*4], *(const float4*)&Bt[tx + 16][k4*4],
            *(const float4*)&Bt[tx + 32][k4*4], *(const float4*)&Bt[tx + 48][k4*4]};
        #pragma unroll
        for (int i = 0; i < 4; ++i)
            #pragma unroll
            for (int u = 0; u < 4; ++u) {
                acc[i][u] = fmaf(av[i].x, bv[u].x, acc[i][u]);
                acc[i][u] = fmaf(av[i].y, bv[u].y, acc[i][u]);
                acc[i][u] = fmaf(av[i].z, bv[u].z, acc[i][u]);
                acc[i][u] = fmaf(av[i].w, bv[u].w, acc[i][u]);
            }
    }

    float bias[4];
    #pragma unroll
    for (int u = 0; u < 4; ++u) bias[u] = b_ih[col0 + tx + 16*u];
    #pragma unroll
    for (int i = 0; i < 4; ++i) {
        const size_t rowoff = (size_t)(row0 + ty + 16*i) * G3;
        #pragma unroll
        for (int u = 0; u < 4; ++u)
            xg[rowoff + col0 + tx + 16*u] = acc[i][u] + bias[u];
    }
}

// ---------------------------------------------------------------------------
// Kernel 3: sequential GRU. 256 blocks x 512 threads (8 waves, 2/SIMD).
// Thread (j in [0,128), q in [0,4)) owns gate rows {j,128+j,256+j} of W_hh,
// cols [q*32,q*32+32).
//
// ROUND-3 FIX (the real bottleneck): VGPR_Count was 72 < 96 weight floats —
// the compiler was RE-LOADING all weights from global EVERY STEP (loop-
// invariant remat heuristic). 256 blocks x 50 steps x 196 KB = 2.5 GB of L2
// reads in 48 us = ~52 TB/s > the ~34.5 TB/s L2 ceiling: the kernel was
// L2-BW-bound on redundant weight traffic, which is why all sync-structure
// changes were invisible. Fix: opaque-value inline asm on each weight float4
// after the load -> compiler cannot rematerialize, must keep 96 VGPRs live
// (budget at launch_bounds(512,2) is 256; no spill).
// Also: __shfl_xor (ds_swizzle, ~120cyc + LDS pipe) -> DPP quad_perm adds
// (pure VALU, q = tid&3 is exactly the hardware quad).
// ---------------------------------------------------------------------------
__global__ __launch_bounds__(512, 2) void gru_kernel(
    const int*   __restrict__ lengths,
    const float* __restrict__ W_hh,
    const float* __restrict__ b_hh,
    const float* __restrict__ h0,
    const float* __restrict__ xg,
    float* __restrict__ out_dyn,
    float* __restrict__ out_h)
{
    __shared__ float hs[2][En];

    const int tid = threadIdx.x;
    const int b   = blockIdx.x;
    const int j   = tid >> 2;        // [0,128)
    const int q   = tid & 3;         // [0,4) — the DPP quad

    // Weight fragments, rotated by q at load time so compute indices are
    // constant; then pinned in VGPRs via opaque asm.
    f32x4 w0[8], w1[8], w2[8];
    {
        const f32x4* p0 = (const f32x4*)(W_hh + (size_t)(0*En + j) * En + q * 32);
        const f32x4* p1 = (const f32x4*)(W_hh + (size_t)(1*En + j) * En + q * 32);
        const f32x4* p2 = (const f32x4*)(W_hh + (size_t)(2*En + j) * En + q * 32);
        #pragma unroll
        for (int c = 0; c < 8; ++c) {
            const int cc = (c + 2*q) & 7;
            w0[c] = p0[cc]; w1[c] = p1[cc]; w2[c] = p2[cc];
        }
    }
    #pragma unroll
    for (int c = 0; c < 8; ++c) {
        asm volatile("" : "+v"(w0[c]), "+v"(w1[c]), "+v"(w2[c]));
    }

    const int len = lengths[b];
    const float* xgb = xg + (size_t)b * Tn * G3;
    float* outb = out_dyn + (size_t)b * Tn * En;

    const float br = b_hh[j], bz = b_hh[En + j], bn = b_hh[2*En + j];
    float hprev = h0[(size_t)b * En + j];
    if (q == 0) hs[0][j] = hprev;

    // xg software pipeline, depth 2: x0 = step t, x1 = step t+1.
    float x0r = xgb[j], x0z = xgb[En + j], x0n = xgb[2*En + j];
    const int t1 = (1 < len) ? 1 : 0;
    float x1r = xgb[t1*G3 + j], x1z = xgb[t1*G3 + En + j], x1n = xgb[t1*G3 + 2*En + j];
    __syncthreads();   // one-time full drain: hs[0] + weights + x0/x1 resident

    int cur = 0;
    for (int t = 0; t < len; ++t) {
        // issue prefetch for t+2 at the top: ~2 steps of latency-hiding window
        const int tn = (t + 2 < len) ? t + 2 : len - 1;
        const float fr  = xgb[tn*G3 + j];
        const float fz  = xgb[tn*G3 + En + j];
        const float fnn = xgb[tn*G3 + 2*En + j];

        // partial dots over this thread's 32-col K-slice (bank-conflict-free
        // via the rotated walk)
        const f32x4* h4 = ((const f32x4*)hs[cur]) + q * 8;
        float a0 = 0.f, a1 = 0.f, a2 = 0.f;
        #pragma unroll
        for (int c = 0; c < 8; ++c) {
            const f32x4 hv = h4[(c + 2*q) & 7];
            a0 = fmaf(w0[c].x, hv.x, a0); a0 = fmaf(w0[c].y, hv.y, a0);
            a0 = fmaf(w0[c].z, hv.z, a0); a0 = fmaf(w0[c].w, hv.w, a0);
            a1 = fmaf(w1[c].x, hv.x, a1); a1 = fmaf(w1[c].y, hv.y, a1);
            a1 = fmaf(w1[c].z, hv.z, a1); a1 = fmaf(w1[c].w, hv.w, a1);
            a2 = fmaf(w2[c].x, hv.x, a2); a2 = fmaf(w2[c].y, hv.y, a2);
            a2 = fmaf(w2[c].z, hv.z, a2); a2 = fmaf(w2[c].w, hv.w, a2);
        }

        // in-quad butterfly reduce over q — DPP, pure VALU
        a0 = quad_reduce_add(a0);
        a1 = quad_reduce_add(a1);
        a2 = quad_reduce_add(a2);

        // gates — computed redundantly by all 4 q-lanes
        const float r = sigmoidf(x0r + br + a0);
        const float z = sigmoidf(x0z + bz + a1);
        const float n = tanh_safe(x0n + r * (bn + a2));
        const float hnew = (1.0f - z) * n + z * hprev;

        if (q == 0) {
            hs[cur ^ 1][j] = hnew;      // write the OTHER buffer
            outb[t*En + j] = hnew;      // fire-and-forget: never drained in-loop
        }
        // Raw barrier: drain LDS only (own reads + the hnew write), leave
        // global loads/stores in flight across the barrier.
        asm volatile("s_waitcnt lgkmcnt(0)" ::: "memory");
        __builtin_amdgcn_s_barrier();
        __builtin_amdgcn_sched_barrier(0);

        hprev = hnew;
        x0r = x1r; x0z = x1z; x0n = x1n;
        x1r = fr;  x1z = fz;  x1n = fnn;
        cur ^= 1;
    }

    if (q == 0) {
        for (int t = len; t < Tn; ++t) outb[t*En + j] = 0.0f;
        out_h[(size_t)b * En + j] = hprev;
    }
}

extern "C" void kernel_launch(void* const* d_in, const int* in_sizes, int n_in,
                              void* d_out, int out_size, void* d_ws, size_t ws_size,
                              hipStream_t stream) {
    const int*   item_ids     = (const int*)d_in[0];
    const int*   basket_sizes = (const int*)d_in[1];
    const int*   lengths      = (const int*)d_in[2];
    const float* emb          = (const float*)d_in[3];
    const float* W_ih         = (const float*)d_in[4];
    const float* W_hh         = (const float*)d_in[5];
    const float* b_ih         = (const float*)d_in[6];
    const float* b_hh         = (const float*)d_in[7];
    const float* h0           = (const float*)d_in[8];
    float* out = (float*)d_out;
    float* xg  = (float*)d_ws;   // 19.7 MB
    float* ub  = out;            // reuse out_dyn region; overwritten by gru later

    gather_kernel<<<(Bn * Tn) / 8, 256, 0, stream>>>(item_ids, basket_sizes, emb, ub);
    gemm_kernel<<<1200, 256, 0, stream>>>(ub, W_ih, b_ih, xg);
    gru_kernel<<<Bn, 512, 0, stream>>>(
        lengths, W_hh, b_hh, h0, xg, out, out + (size_t)Bn * Tn * En);
}